// Round 4
// baseline (264.888 us; speedup 1.0000x reference)
//
#include <hip/hip_runtime.h>
#include <stdint.h>

#define MB 8192
#define KD 256
#define BM 128            // rows per block: 4 waves x 32 rows (rt=2, proven R2 shape)
#define BN 64             // cols per chunk
#define NSPLIT 16         // column slabs -> 1024 blocks = 4/CU
#define SLAB 512          // MB/NSPLIT
#define CHUNKS 8          // SLAB/BN
#define GRIDX 64          // MB/BM
#define NBLOCKS (GRIDX * NSPLIT)
#define COFF 104.0f       // fixed exp offset: overflow/underflow-safe (verified R1-R3)
#define LOG2E 1.44269504088896340736f

typedef __attribute__((ext_vector_type(8))) short bf16x8;
typedef __attribute__((ext_vector_type(4))) float f32x4;

typedef const __attribute__((address_space(1))) uint32_t* gptr_t;
typedef __attribute__((address_space(3))) uint32_t* lptr_t;

__device__ __forceinline__ unsigned short f2bf(float x) {
  union { float f; uint32_t u; } v; v.f = x;
  uint32_t r = v.u + 0x7fffu + ((v.u >> 16) & 1u);   // RNE
  return (unsigned short)(r >> 16);
}

__device__ __forceinline__ float fast_exp2(float x) {
#if __has_builtin(__builtin_amdgcn_exp2f)
  return __builtin_amdgcn_exp2f(x);
#else
  return exp2f(x);
#endif
}

// ---- prep: fp32->bf16 A,B; pos_sim; b2 = (-log q - C)*log2e; zero ps/pc/counter ----
__global__ __launch_bounds__(256) void prep_kernel(
    const float* __restrict__ A, const float* __restrict__ B,
    const float* __restrict__ q,
    unsigned short* __restrict__ Abf, unsigned short* __restrict__ Bbf,
    float* __restrict__ b2, float* __restrict__ pos,
    float* __restrict__ ps, float* __restrict__ pc,
    unsigned int* __restrict__ counter) {
  int t = blockIdx.x * 256 + threadIdx.x;        // 524288 threads, 1 float4 each
  const float4 a = ((const float4*)A)[t];
  const float4 b = ((const float4*)B)[t];
  ushort4 oa, ob;
  oa.x = f2bf(a.x); oa.y = f2bf(a.y); oa.z = f2bf(a.z); oa.w = f2bf(a.w);
  ob.x = f2bf(b.x); ob.y = f2bf(b.y); ob.z = f2bf(b.z); ob.w = f2bf(b.w);
  ((ushort4*)Abf)[t] = oa;
  ((ushort4*)Bbf)[t] = ob;
  // pos_sim: wave (t>>6) == row
  float d = a.x * b.x + a.y * b.y + a.z * b.z + a.w * b.w;
  #pragma unroll
  for (int off = 32; off; off >>= 1) d += __shfl_down(d, off, 64);
  if ((threadIdx.x & 63) == 0) pos[t >> 6] = d;
  if (t < MB) {
    b2[t] = (-logf(q[t]) - COFF) * LOG2E;
    ps[t] = 0.0f;
    pc[t] = 0.0f;
  }
  if (t == 0) *counter = 0u;
}

// ---- fused GEMM + masked fixed-offset exp-sum + match count + last-block finalize ----
__global__ __launch_bounds__(256, 3) void fused_kernel(
    const unsigned short* __restrict__ Abf,
    const unsigned short* __restrict__ Bbf,
    const int* __restrict__ ids,
    const float* __restrict__ b2,
    const float* __restrict__ pos,
    const float* __restrict__ q,
    float* __restrict__ ps, float* __restrict__ pc,
    unsigned int* __restrict__ counter,
    float* __restrict__ out) {
  const int tid = threadIdx.x;
  const int wave = tid >> 6, lane = tid & 63, quad = lane >> 4, lpos = lane & 15;
  const int rowbase = blockIdx.x * BM + wave * 32;
  const int colbase = blockIdx.y * SLAB;

  // Fragment-ordered B staging: cell c = ct*512 + kb*64 + quad*16 + lpos at Bs+16c.
  // Frag reads are lane-linear (lane i -> byte 16i): conflict-free ds_read_b128.
  // Staging dest c = tid + s8*256 is lane-linear too -> global_load_lds legal.
  __shared__ unsigned short Bs[2048 * 8];    // 32 KB

  // A fragments resident: wave owns rows [rowbase, rowbase+32)  (64 VGPRs)
  bf16x8 afrag[2][8];
  #pragma unroll
  for (int rt = 0; rt < 2; ++rt)
    #pragma unroll
    for (int kb = 0; kb < 8; ++kb)
      afrag[rt][kb] = *(const bf16x8*)(Abf + (size_t)(rowbase + rt * 16 + lpos) * KD + kb * 32 + quad * 8);

  int idr[2][4];
  float srun[2][4];
  int crun[2];                   // packed per-r byte counts of id-matches (max 32/lane: safe)
  #pragma unroll
  for (int rt = 0; rt < 2; ++rt) {
    crun[rt] = 0;
    #pragma unroll
    for (int r = 0; r < 4; ++r) {
      idr[rt][r] = ids[rowbase + rt * 16 + quad * 4 + r];
      srun[rt][r] = 0.0f;
    }
  }

  // staging sources: s8 = 2*ct + h; cell c = tid + s8*256 reads
  // Bbf[(colbase + ct*16 + lp)*KD + (kb0 + 4h)*32 + qd*8]
  const int lp = tid & 15, qd = (tid >> 4) & 3, kb0 = (tid >> 6) & 3;
  const unsigned short* srcct[4];
  #pragma unroll
  for (int ct = 0; ct < 4; ++ct)
    srcct[ct] = Bbf + (size_t)(colbase + ct * 16 + lp) * KD + kb0 * 32 + qd * 8;

  for (int ch = 0; ch < CHUNKS; ++ch) {
    __syncthreads();                         // Bs safe to overwrite
    #pragma unroll
    for (int ct = 0; ct < 4; ++ct) {
      #pragma unroll
      for (int h = 0; h < 2; ++h) {
        const int s8 = ct * 2 + h;
        __builtin_amdgcn_global_load_lds(
            (gptr_t)(const void*)(srcct[ct] + h * 128),
            (lptr_t)(void*)(Bs + (size_t)(tid + s8 * 256) * 8),
            16, 0, 0);
      }
      srcct[ct] += BN * KD;                  // advance to next chunk
    }
    __syncthreads();                         // loads landed

    const int colchunk = colbase + ch * BN;
    #pragma unroll
    for (int ct = 0; ct < 4; ++ct) {
      bf16x8 bfrag[8];
      #pragma unroll
      for (int kb = 0; kb < 8; ++kb)
        bfrag[kb] = *(const bf16x8*)(Bs + (size_t)(ct * 512 + kb * 64 + quad * 16 + lpos) * 8);
      f32x4 acc[2] = {{0,0,0,0},{0,0,0,0}};
      #pragma unroll
      for (int kb = 0; kb < 8; ++kb)
        #pragma unroll
        for (int rt = 0; rt < 2; ++rt)       // 2 independent chains
          acc[rt] = __builtin_amdgcn_mfma_f32_16x16x32_bf16(afrag[rt][kb], bfrag[kb], acc[rt], 0, 0, 0);
      const int j = colchunk + ct * 16 + lpos;
      const int idj = ids[j];
      const float bj = b2[j];
      #pragma unroll
      for (int rt = 0; rt < 2; ++rt)
        #pragma unroll
        for (int r = 0; r < 4; ++r) {
          const bool match = (idj == idr[rt][r]);
          const float x = fmaf(acc[rt][r], LOG2E, bj);
          srun[rt][r] += fast_exp2(match ? -1000.0f : x);   // exp2(-1000)=0
          crun[rt] += match ? (1 << (8 * r)) : 0;
        }
    }
  }

  // reduce (s, matches) across the 16 lpos lanes of each quad; one atomic per row
  #pragma unroll
  for (int rt = 0; rt < 2; ++rt)
    #pragma unroll
    for (int r = 0; r < 4; ++r) {
      float s = srun[rt][r];
      float c = (float)((crun[rt] >> (8 * r)) & 255);
      #pragma unroll
      for (int off = 1; off < 16; off <<= 1) {
        s += __shfl_xor(s, off, 64);
        c += __shfl_xor(c, off, 64);
      }
      if (lpos == 0) {
        const int gi = rowbase + rt * 16 + quad * 4 + r;
        atomicAdd(&ps[gi], s);
        atomicAdd(&pc[gi], c);
      }
    }

  // ---- last-block finalize ----
  __threadfence();                 // make this block's atomics device-visible
  __syncthreads();                 // all threads' fences precede the counter bump
  __shared__ unsigned int done_s;
  if (tid == 0)
    done_s = __hip_atomic_fetch_add(counter, 1u, __ATOMIC_ACQ_REL, __HIP_MEMORY_SCOPE_AGENT);
  __syncthreads();
  if (done_s == NBLOCKS - 1) {
    float acc = 0.0f;
    for (int i = tid; i < MB; i += 256) {
      const float s  = __hip_atomic_load(&ps[i], __ATOMIC_RELAXED, __HIP_MEMORY_SCOPE_AGENT);
      const float cm = __hip_atomic_load(&pc[i], __ATOMIC_RELAXED, __HIP_MEMORY_SCOPE_AGENT);
      const float nm = (float)MB - cm;       // n_miss
      const float z = logf(s) + COFF + log1pf(-q[i]) - logf(nm);
      const float p = pos[i];
      const float hi = fmaxf(p, z), lo = fminf(p, z);
      acc += -p + hi + log1pf(__expf(lo - hi));
    }
    #pragma unroll
    for (int off = 32; off; off >>= 1) acc += __shfl_down(acc, off, 64);
    __shared__ float red[4];
    if (lane == 0) red[wave] = acc;
    __syncthreads();
    if (tid == 0) out[0] = (red[0] + red[1] + red[2] + red[3]) * (1.0f / (float)MB);
  }
}

extern "C" void kernel_launch(void* const* d_in, const int* in_sizes, int n_in,
                              void* d_out, int out_size, void* d_ws, size_t ws_size,
                              hipStream_t stream) {
  (void)in_sizes; (void)n_in; (void)out_size; (void)ws_size;
  const float* input_emb  = (const float*)d_in[0];
  const float* target_emb = (const float*)d_in[1];
  const int*   target_ids = (const int*)d_in[2];
  const float* q_probas   = (const float*)d_in[3];
  float* out = (float*)d_out;

  char* ws = (char*)d_ws;
  unsigned short* Abf = (unsigned short*)(ws);                    // 4 MB
  unsigned short* Bbf = (unsigned short*)(ws + (4u << 20));       // 4 MB
  float* b2   = (float*)(ws + (8u << 20));                        // 32 KB
  float* pos  = (float*)(ws + (8u << 20) + 32768);                // 32 KB
  float* ps   = (float*)(ws + (8u << 20) + 65536);                // 32 KB
  float* pc   = (float*)(ws + (8u << 20) + 98304);                // 32 KB
  unsigned int* counter = (unsigned int*)(ws + (8u << 20) + 131072);

  prep_kernel<<<2048, 256, 0, stream>>>(input_emb, target_emb, q_probas,
                                        Abf, Bbf, b2, pos, ps, pc, counter);
  fused_kernel<<<dim3(GRIDX, NSPLIT), 256, 0, stream>>>(
      Abf, Bbf, target_ids, b2, pos, q_probas, ps, pc, counter, out);
}

// Round 5
// 145.557 us; speedup vs baseline: 1.8198x; 1.8198x over previous
//
#include <hip/hip_runtime.h>
#include <stdint.h>

#define MB 8192
#define KD 256
#define BM 128            // rows per block: 4 waves x 32 rows (rt=2, proven R2 shape)
#define BN 64             // cols per chunk
#define NSPLIT 16         // column slabs -> 1024 blocks = exactly 4/CU resident
#define SLAB 512          // MB/NSPLIT
#define CHUNKS 8          // SLAB/BN
#define GRIDX 64          // MB/BM
#define COFF 104.0f       // fixed exp offset: overflow/underflow-safe (verified R1-R4)
#define LOG2E 1.44269504088896340736f

typedef __attribute__((ext_vector_type(8))) short bf16x8;
typedef __attribute__((ext_vector_type(4))) float f32x4;

typedef const __attribute__((address_space(1))) uint32_t* gptr_t;
typedef __attribute__((address_space(3))) uint32_t* lptr_t;

__device__ __forceinline__ unsigned short f2bf(float x) {
  union { float f; uint32_t u; } v; v.f = x;
  uint32_t r = v.u + 0x7fffu + ((v.u >> 16) & 1u);   // RNE
  return (unsigned short)(r >> 16);
}

__device__ __forceinline__ float fast_exp2(float x) {
#if __has_builtin(__builtin_amdgcn_exp2f)
  return __builtin_amdgcn_exp2f(x);
#else
  return exp2f(x);
#endif
}

// ---- prep: fp32->bf16 A,B; pos_sim; b2 = (-log q - C)*log2e; zero ps/pc ----
__global__ __launch_bounds__(256) void prep_kernel(
    const float* __restrict__ A, const float* __restrict__ B,
    const float* __restrict__ q,
    unsigned short* __restrict__ Abf, unsigned short* __restrict__ Bbf,
    float* __restrict__ b2, float* __restrict__ pos,
    float* __restrict__ ps, float* __restrict__ pc) {
  int t = blockIdx.x * 256 + threadIdx.x;        // 524288 threads, 1 float4 each
  const float4 a = ((const float4*)A)[t];
  const float4 b = ((const float4*)B)[t];
  ushort4 oa, ob;
  oa.x = f2bf(a.x); oa.y = f2bf(a.y); oa.z = f2bf(a.z); oa.w = f2bf(a.w);
  ob.x = f2bf(b.x); ob.y = f2bf(b.y); ob.z = f2bf(b.z); ob.w = f2bf(b.w);
  ((ushort4*)Abf)[t] = oa;
  ((ushort4*)Bbf)[t] = ob;
  // pos_sim: wave (t>>6) == row
  float d = a.x * b.x + a.y * b.y + a.z * b.z + a.w * b.w;
  #pragma unroll
  for (int off = 32; off; off >>= 1) d += __shfl_down(d, off, 64);
  if ((threadIdx.x & 63) == 0) pos[t >> 6] = d;
  if (t < MB) {
    b2[t] = (-logf(q[t]) - COFF) * LOG2E;
    ps[t] = 0.0f;
    pc[t] = 0.0f;
  }
}

// ---- fused GEMM + masked fixed-offset exp-sum + match count ----
__global__ __launch_bounds__(256, 4) void fused_kernel(
    const unsigned short* __restrict__ Abf,
    const unsigned short* __restrict__ Bbf,
    const int* __restrict__ ids,
    const float* __restrict__ b2,
    float* __restrict__ ps, float* __restrict__ pc) {
  const int tid = threadIdx.x;
  const int wave = tid >> 6, lane = tid & 63, quad = lane >> 4, lpos = lane & 15;
  const int rowbase = blockIdx.x * BM + wave * 32;
  const int colbase = blockIdx.y * SLAB;

  // Fragment-ordered B staging: cell c = ct*512 + kb*64 + quad*16 + lpos at Bs+16c.
  // Frag reads are lane-linear (lane i -> byte 16i): conflict-free ds_read_b128.
  // Staging dest c = tid + s8*256 is lane-linear too -> global_load_lds legal.
  __shared__ unsigned short Bs[2048 * 8];    // 32 KB

  // A fragments resident: wave owns rows [rowbase, rowbase+32)  (64 VGPRs)
  bf16x8 afrag[2][8];
  #pragma unroll
  for (int rt = 0; rt < 2; ++rt)
    #pragma unroll
    for (int kb = 0; kb < 8; ++kb)
      afrag[rt][kb] = *(const bf16x8*)(Abf + (size_t)(rowbase + rt * 16 + lpos) * KD + kb * 32 + quad * 8);

  int idr[2][4];
  float srun[2][4];
  int crun[2];                   // packed per-r byte counts of id-matches (max 32/lane: safe)
  #pragma unroll
  for (int rt = 0; rt < 2; ++rt) {
    crun[rt] = 0;
    #pragma unroll
    for (int r = 0; r < 4; ++r) {
      idr[rt][r] = ids[rowbase + rt * 16 + quad * 4 + r];
      srun[rt][r] = 0.0f;
    }
  }

  // staging sources: s8 = 2*ct + h; cell c = tid + s8*256 reads
  // Bbf[(colbase + ct*16 + lp)*KD + (kb0 + 4h)*32 + qd*8]
  const int lp = tid & 15, qd = (tid >> 4) & 3, kb0 = (tid >> 6) & 3;
  const unsigned short* srcct[4];
  #pragma unroll
  for (int ct = 0; ct < 4; ++ct)
    srcct[ct] = Bbf + (size_t)(colbase + ct * 16 + lp) * KD + kb0 * 32 + qd * 8;

  for (int ch = 0; ch < CHUNKS; ++ch) {
    __syncthreads();                         // Bs safe to overwrite
    #pragma unroll
    for (int ct = 0; ct < 4; ++ct) {
      #pragma unroll
      for (int h = 0; h < 2; ++h) {
        const int s8 = ct * 2 + h;
        __builtin_amdgcn_global_load_lds(
            (gptr_t)(const void*)(srcct[ct] + h * 128),
            (lptr_t)(void*)(Bs + (size_t)(tid + s8 * 256) * 8),
            16, 0, 0);
      }
      srcct[ct] += BN * KD;                  // advance to next chunk
    }
    __syncthreads();                         // loads landed

    const int colchunk = colbase + ch * BN;
    #pragma unroll
    for (int ct = 0; ct < 4; ++ct) {
      bf16x8 bfrag[8];
      #pragma unroll
      for (int kb = 0; kb < 8; ++kb)
        bfrag[kb] = *(const bf16x8*)(Bs + (size_t)(ct * 512 + kb * 64 + quad * 16 + lpos) * 8);
      f32x4 acc[2] = {{0,0,0,0},{0,0,0,0}};
      #pragma unroll
      for (int kb = 0; kb < 8; ++kb)
        #pragma unroll
        for (int rt = 0; rt < 2; ++rt)       // 2 independent chains
          acc[rt] = __builtin_amdgcn_mfma_f32_16x16x32_bf16(afrag[rt][kb], bfrag[kb], acc[rt], 0, 0, 0);
      const int j = colchunk + ct * 16 + lpos;
      const int idj = ids[j];
      const float bj = b2[j];
      #pragma unroll
      for (int rt = 0; rt < 2; ++rt)
        #pragma unroll
        for (int r = 0; r < 4; ++r) {
          const bool match = (idj == idr[rt][r]);
          const float x = fmaf(acc[rt][r], LOG2E, bj);
          srun[rt][r] += fast_exp2(match ? -1000.0f : x);   // exp2(-1000)=0
          crun[rt] += match ? (1 << (8 * r)) : 0;
        }
    }
  }

  // reduce (s, matches) across the 16 lpos lanes of each quad; one atomic per row
  #pragma unroll
  for (int rt = 0; rt < 2; ++rt)
    #pragma unroll
    for (int r = 0; r < 4; ++r) {
      float s = srun[rt][r];
      float c = (float)((crun[rt] >> (8 * r)) & 255);
      #pragma unroll
      for (int off = 1; off < 16; off <<= 1) {
        s += __shfl_xor(s, off, 64);
        c += __shfl_xor(c, off, 64);
      }
      if (lpos == 0) {
        const int gi = rowbase + rt * 16 + quad * 4 + r;
        atomicAdd(&ps[gi], s);        // relaxed device-scope: no cache fences
        atomicAdd(&pc[gi], c);
      }
    }
}

// ---- finalize: per-row loss, mean (kernel boundary provides coherence) ----
__global__ __launch_bounds__(256) void finalize_kernel(
    const float* __restrict__ ps, const float* __restrict__ pc,
    const float* __restrict__ pos, const float* __restrict__ q,
    float* __restrict__ out) {
  int i = blockIdx.x * 256 + threadIdx.x;   // 32 blocks -> 8192 threads
  const float s = ps[i];
  const float nm = (float)MB - pc[i];       // n_miss
  const float z = logf(s) + COFF + log1pf(-q[i]) - logf(nm);
  const float p = pos[i];
  const float hi = fmaxf(p, z), lo = fminf(p, z);
  float loss = -p + hi + log1pf(__expf(lo - hi));

  #pragma unroll
  for (int off = 32; off; off >>= 1) loss += __shfl_down(loss, off, 64);
  __shared__ float red[4];
  if ((threadIdx.x & 63) == 0) red[threadIdx.x >> 6] = loss;
  __syncthreads();
  if (threadIdx.x == 0) {
    float t = red[0] + red[1] + red[2] + red[3];
    atomicAdd(out, t * (1.0f / (float)MB));
  }
}

extern "C" void kernel_launch(void* const* d_in, const int* in_sizes, int n_in,
                              void* d_out, int out_size, void* d_ws, size_t ws_size,
                              hipStream_t stream) {
  (void)in_sizes; (void)n_in; (void)out_size; (void)ws_size;
  const float* input_emb  = (const float*)d_in[0];
  const float* target_emb = (const float*)d_in[1];
  const int*   target_ids = (const int*)d_in[2];
  const float* q_probas   = (const float*)d_in[3];
  float* out = (float*)d_out;

  char* ws = (char*)d_ws;
  unsigned short* Abf = (unsigned short*)(ws);                    // 4 MB
  unsigned short* Bbf = (unsigned short*)(ws + (4u << 20));       // 4 MB
  float* b2   = (float*)(ws + (8u << 20));                        // 32 KB
  float* pos  = (float*)(ws + (8u << 20) + 32768);                // 32 KB
  float* ps   = (float*)(ws + (8u << 20) + 65536);                // 32 KB
  float* pc   = (float*)(ws + (8u << 20) + 98304);                // 32 KB

  hipMemsetAsync(out, 0, sizeof(float), stream);
  prep_kernel<<<2048, 256, 0, stream>>>(input_emb, target_emb, q_probas,
                                        Abf, Bbf, b2, pos, ps, pc);
  fused_kernel<<<dim3(GRIDX, NSPLIT), 256, 0, stream>>>(
      Abf, Bbf, target_ids, b2, ps, pc);
  finalize_kernel<<<32, 256, 0, stream>>>(ps, pc, pos, q_probas, out);
}